// Round 2
// baseline (3747.123 us; speedup 1.0000x reference)
//
#include <hip/hip_runtime.h>
#include <hip/hip_bf16.h>

#define DD 64
#define XPAD 68   // padded leading dim for transposed x tile (multiple of 4, not of 32)

// W[r,i,o] = sum_b coeff[r,b] * basis[b,i,o]
__global__ __launch_bounds__(256) void compute_w_kernel(
    const float* __restrict__ basis,   // [B,D,D]
    const float* __restrict__ coeff,   // [R,B]
    float* __restrict__ W,             // [R,D,D]
    int Rn, int Bn) {
  int idx = blockIdx.x * 256 + threadIdx.x;
  if (idx >= Rn * DD * DD) return;
  int r = idx / (DD * DD);
  int io = idx - r * DD * DD;
  float acc = 0.f;
  for (int b = 0; b < Bn; ++b)
    acc += coeff[r * Bn + b] * basis[b * DD * DD + io];
  W[idx] = acc;
}

// One block = 64 nodes x 64 outputs for one weight matrix.
// blockIdx.y in [0, cs) -> relation rel (write h), == cs -> self path (write out_buf + bias).
__global__ __launch_bounds__(256) void transform_kernel(
    const float* __restrict__ x,        // [N,D]
    const float* __restrict__ Wchunk,   // [cs,D,D]
    const float* __restrict__ self_w,   // [D,D]
    const float* __restrict__ bias_l,   // [D]
    float* __restrict__ h,              // [cs,N,D]
    float* __restrict__ out_buf,        // [N,D]
    int N, int cs) {
  __shared__ __align__(16) float Ws[DD * DD];
  __shared__ __align__(16) float xsT[DD * XPAD];   // [i][node_local], padded

  const int t = threadIdx.x;
  const int rel = blockIdx.y;
  const bool is_self = (rel == cs);
  const float* Wsrc = is_self ? self_w : (Wchunk + (size_t)rel * DD * DD);

  for (int j = t; j < DD * DD; j += 256) Ws[j] = Wsrc[j];

  const int nbase = blockIdx.x * DD;
  for (int j = t; j < DD * DD; j += 256) {
    int nl = j >> 6;        // node local 0..63
    int i  = j & 63;        // feature
    int n  = nbase + nl;
    xsT[i * XPAD + nl] = (n < N) ? x[(size_t)n * DD + i] : 0.f;
  }
  __syncthreads();

  const int o0 = (t & 15) * 4;   // 4 consecutive outputs
  const int n0 = (t >> 4) * 4;   // 4 consecutive local nodes

  float acc[4][4];
#pragma unroll
  for (int a = 0; a < 4; ++a)
#pragma unroll
    for (int b = 0; b < 4; ++b) acc[a][b] = 0.f;

#pragma unroll 4
  for (int i = 0; i < DD; ++i) {
    float4 wv = *reinterpret_cast<const float4*>(&Ws[i * DD + o0]);
    float4 xv = *reinterpret_cast<const float4*>(&xsT[i * XPAD + n0]);
    float xa[4] = {xv.x, xv.y, xv.z, xv.w};
    float wa[4] = {wv.x, wv.y, wv.z, wv.w};
#pragma unroll
    for (int a = 0; a < 4; ++a)
#pragma unroll
      for (int b = 0; b < 4; ++b) acc[a][b] += xa[a] * wa[b];
  }

  float4 bv = make_float4(0.f, 0.f, 0.f, 0.f);
  if (is_self) bv = *reinterpret_cast<const float4*>(&bias_l[o0]);
  float* dst = is_self ? out_buf : (h + (size_t)rel * N * DD);

#pragma unroll
  for (int a = 0; a < 4; ++a) {
    int n = nbase + n0 + a;
    if (n < N) {
      float4 ov = make_float4(acc[a][0] + bv.x, acc[a][1] + bv.y,
                              acc[a][2] + bv.z, acc[a][3] + bv.w);
      *reinterpret_cast<float4*>(&dst[(size_t)n * DD + o0]) = ov;
    }
  }
}

// 16 threads per edge, float4 gather from h + 4 scalar fp32 atomics into out_buf.
__global__ __launch_bounds__(256) void edge_scatter_kernel(
    const int* __restrict__ esrc, const int* __restrict__ edst,
    const int* __restrict__ et,
    const float* __restrict__ h,        // [r1-r0, N, D]
    float* __restrict__ out_buf,        // [N,D]
    int E, int N, int r0, int r1) {
  long long tid = (long long)blockIdx.x * 256 + threadIdx.x;
  int e = (int)(tid >> 4);
  int g = (int)(tid & 15);
  if (e >= E) return;
  int ty = et[e];
  if (ty < r0 || ty >= r1) return;
  int s = esrc[e];
  int d = edst[e];
  const float4 v = *reinterpret_cast<const float4*>(
      h + ((size_t)(ty - r0) * N + (size_t)s) * DD + g * 4);
  float* o = out_buf + (size_t)d * DD + g * 4;
  atomicAdd(o + 0, v.x);
  atomicAdd(o + 1, v.y);
  atomicAdd(o + 2, v.z);
  atomicAdd(o + 3, v.w);
}

__global__ __launch_bounds__(256) void relu_kernel(float* __restrict__ buf, int n4) {
  int i = blockIdx.x * 256 + threadIdx.x;
  if (i >= n4) return;
  float4 v = reinterpret_cast<float4*>(buf)[i];
  v.x = fmaxf(v.x, 0.f);
  v.y = fmaxf(v.y, 0.f);
  v.z = fmaxf(v.z, 0.f);
  v.w = fmaxf(v.w, 0.f);
  reinterpret_cast<float4*>(buf)[i] = v;
}

extern "C" void kernel_launch(void* const* d_in, const int* in_sizes, int n_in,
                              void* d_out, int out_size, void* d_ws, size_t ws_size,
                              hipStream_t stream) {
  const float* x0     = (const float*)d_in[0];  // [N,D]
  const float* basis  = (const float*)d_in[1];  // [L,B,D,D]
  const float* coeff  = (const float*)d_in[2];  // [L,R,B]
  const float* self_w = (const float*)d_in[3];  // [L,D,D]
  const float* bias   = (const float*)d_in[4];  // [L,D]
  const int*   eidx   = (const int*)d_in[5];    // [2,E]
  const int*   etyp   = (const int*)d_in[6];    // [E]

  const int N  = in_sizes[0] / DD;
  const int L  = in_sizes[4] / DD;
  const int Bn = in_sizes[1] / (L * DD * DD);
  const int R  = in_sizes[2] / (L * Bn);
  const int E  = in_sizes[6];

  float* ws   = (float*)d_ws;
  float* Wbuf = ws;                                  // R*D*D
  float* A    = Wbuf + (size_t)R * DD * DD;          // [N,D] layer-0 output
  float* h    = A + (size_t)N * DD;                  // [chunk,N,D]

  // Relation chunk size that fits in the remaining workspace (deterministic in ws_size).
  size_t avail = ws_size / sizeof(float);
  size_t fixed = (size_t)R * DD * DD + (size_t)N * DD;
  int chunk = 1;
  if (avail > fixed + (size_t)N * DD) {
    size_t c = (avail - fixed) / ((size_t)N * DD);
    chunk = (int)(c > (size_t)R ? (size_t)R : c);
  }

  const int* esrc = eidx;
  const int* edst = eidx + E;

  const int nb_x  = (N + DD - 1) / DD;               // transform grid.x
  const int nb_e  = (int)(((long long)E * 16 + 255) / 256);
  const int n4    = (N * DD) / 4;

  for (int l = 0; l < L; ++l) {
    const float* xin = (l == 0) ? x0 : A;
    float* outf      = (l == L - 1) ? (float*)d_out : A;

    compute_w_kernel<<<(R * DD * DD + 255) / 256, 256, 0, stream>>>(
        basis + (size_t)l * Bn * DD * DD, coeff + (size_t)l * R * Bn, Wbuf, R, Bn);

    for (int c0 = 0; c0 < R; c0 += chunk) {
      int cs = (R - c0 < chunk) ? (R - c0) : chunk;
      int gy = cs + ((c0 == 0) ? 1 : 0);   // append self-loop block on first chunk
      transform_kernel<<<dim3(nb_x, gy), 256, 0, stream>>>(
          xin, Wbuf + (size_t)c0 * DD * DD, self_w + (size_t)l * DD * DD,
          bias + (size_t)l * DD, h, outf, N, cs);
      edge_scatter_kernel<<<nb_e, 256, 0, stream>>>(
          esrc, edst, etyp, h, outf, E, N, c0, c0 + cs);
    }

    relu_kernel<<<(n4 + 255) / 256, 256, 0, stream>>>(outf, n4);
  }
}

// Round 3
// 960.600 us; speedup vs baseline: 3.9008x; 3.9008x over previous
//
#include <hip/hip_runtime.h>

#define DD 64
#define XPAD 68   // padded leading dim for transposed x tile

typedef unsigned int u32;

// ---------------- preprocessing: CSR by destination ----------------

__global__ __launch_bounds__(256) void zero_u32_kernel(u32* __restrict__ p, int n) {
  int i = blockIdx.x * 256 + threadIdx.x;
  if (i < n) p[i] = 0u;
}

__global__ __launch_bounds__(256) void hist_kernel(const int* __restrict__ edst,
                                                   u32* __restrict__ cnt, int E) {
  int e = blockIdx.x * 256 + threadIdx.x;
  if (e < E) atomicAdd(&cnt[edst[e]], 1u);
}

// Per-block exclusive scan of 1024 counts; block totals to partials.
__global__ __launch_bounds__(1024) void scan1_kernel(const u32* __restrict__ cnt,
                                                     u32* __restrict__ row_ptr,
                                                     u32* __restrict__ partials, int N) {
  __shared__ u32 s[1024];
  int t = threadIdx.x;
  int gid = blockIdx.x * 1024 + t;
  u32 v = (gid < N) ? cnt[gid] : 0u;
  s[t] = v;
  __syncthreads();
  for (int off = 1; off < 1024; off <<= 1) {
    u32 x = (t >= off) ? s[t - off] : 0u;
    __syncthreads();
    s[t] += x;
    __syncthreads();
  }
  if (gid < N) row_ptr[gid] = s[t] - v;          // exclusive within block
  if (t == 1023) partials[blockIdx.x] = s[1023]; // block total
}

__global__ void scan2_kernel(u32* __restrict__ partials, int nb) {
  if (threadIdx.x == 0 && blockIdx.x == 0) {
    u32 acc = 0;
    for (int i = 0; i < nb; ++i) { u32 v = partials[i]; partials[i] = acc; acc += v; }
  }
}

__global__ __launch_bounds__(1024) void scan3_kernel(u32* __restrict__ row_ptr,
                                                     const u32* __restrict__ partials,
                                                     int N, int E) {
  int gid = blockIdx.x * 1024 + threadIdx.x;
  if (gid < N) row_ptr[gid] += partials[blockIdx.x];
  else if (gid == N) row_ptr[N] = (u32)E;
}

__global__ __launch_bounds__(256) void scatter_kernel(const int* __restrict__ esrc,
                                                      const int* __restrict__ edst,
                                                      const int* __restrict__ et,
                                                      const u32* __restrict__ row_ptr,
                                                      u32* __restrict__ fill,
                                                      u32* __restrict__ packed, int E) {
  int e = blockIdx.x * 256 + threadIdx.x;
  if (e >= E) return;
  int d = edst[e];
  u32 pos = row_ptr[d] + atomicAdd(&fill[d], 1u);
  packed[pos] = (u32)esrc[e] | ((u32)et[e] << 17);   // src < 2^17, ty < 8
}

// ---------------- per-layer compute ----------------

// W[r,i,o] = sum_b coeff[r,b] * basis[b,i,o]
__global__ __launch_bounds__(256) void compute_w_kernel(
    const float* __restrict__ basis, const float* __restrict__ coeff,
    float* __restrict__ W, int Rn, int Bn) {
  int idx = blockIdx.x * 256 + threadIdx.x;
  if (idx >= Rn * DD * DD) return;
  int r = idx / (DD * DD);
  int io = idx - r * DD * DD;
  float acc = 0.f;
  for (int b = 0; b < Bn; ++b)
    acc += coeff[r * Bn + b] * basis[b * DD * DD + io];
  W[idx] = acc;
}

// One block = 64 nodes x 64 outputs for one weight matrix.
// blockIdx.y in [0, cs) -> relation rel (write h), == cs -> self path (write out_buf + bias).
__global__ __launch_bounds__(256) void transform_kernel(
    const float* __restrict__ x, const float* __restrict__ Wchunk,
    const float* __restrict__ self_w, const float* __restrict__ bias_l,
    float* __restrict__ h, float* __restrict__ out_buf, int N, int cs) {
  __shared__ __align__(16) float Ws[DD * DD];
  __shared__ __align__(16) float xsT[DD * XPAD];

  const int t = threadIdx.x;
  const int rel = blockIdx.y;
  const bool is_self = (rel == cs);
  const float* Wsrc = is_self ? self_w : (Wchunk + (size_t)rel * DD * DD);

  for (int j = t; j < DD * DD; j += 256) Ws[j] = Wsrc[j];

  const int nbase = blockIdx.x * DD;
  for (int j = t; j < DD * DD; j += 256) {
    int nl = j >> 6;
    int i  = j & 63;
    int n  = nbase + nl;
    xsT[i * XPAD + nl] = (n < N) ? x[(size_t)n * DD + i] : 0.f;
  }
  __syncthreads();

  const int o0 = (t & 15) * 4;
  const int n0 = (t >> 4) * 4;

  float acc[4][4];
#pragma unroll
  for (int a = 0; a < 4; ++a)
#pragma unroll
    for (int b = 0; b < 4; ++b) acc[a][b] = 0.f;

#pragma unroll 4
  for (int i = 0; i < DD; ++i) {
    float4 wv = *reinterpret_cast<const float4*>(&Ws[i * DD + o0]);
    float4 xv = *reinterpret_cast<const float4*>(&xsT[i * XPAD + n0]);
    float xa[4] = {xv.x, xv.y, xv.z, xv.w};
    float wa[4] = {wv.x, wv.y, wv.z, wv.w};
#pragma unroll
    for (int a = 0; a < 4; ++a)
#pragma unroll
      for (int b = 0; b < 4; ++b) acc[a][b] += xa[a] * wa[b];
  }

  float4 bv = make_float4(0.f, 0.f, 0.f, 0.f);
  if (is_self) bv = *reinterpret_cast<const float4*>(&bias_l[o0]);
  float* dst = is_self ? out_buf : (h + (size_t)rel * N * DD);

#pragma unroll
  for (int a = 0; a < 4; ++a) {
    int n = nbase + n0 + a;
    if (n < N) {
      float4 ov = make_float4(acc[a][0] + bv.x, acc[a][1] + bv.y,
                              acc[a][2] + bv.z, acc[a][3] + bv.w);
      *reinterpret_cast<float4*>(&dst[(size_t)n * DD + o0]) = ov;
    }
  }
}

// One wave per destination node; lane = feature. Non-atomic accumulate into out.
__global__ __launch_bounds__(256) void aggregate_kernel(
    const u32* __restrict__ packed, const u32* __restrict__ row_ptr,
    const float* __restrict__ h, float* __restrict__ out,
    int N, int r0, int r1) {
  int wid  = (blockIdx.x * 256 + threadIdx.x) >> 6;
  int lane = threadIdx.x & 63;
  if (wid >= N) return;
  u32 beg = row_ptr[wid], end = row_ptr[wid + 1];
  float sum = 0.f;
  for (u32 e = beg; e < end; ++e) {
    u32 p = packed[e];
    int ty = (int)(p >> 17);
    if (ty < r0 || ty >= r1) continue;
    int src = (int)(p & 0x1FFFFu);
    sum += h[((size_t)(ty - r0) * N + src) * DD + lane];
  }
  out[(size_t)wid * DD + lane] += sum;
}

__global__ __launch_bounds__(256) void relu_kernel(float* __restrict__ buf, int n4) {
  int i = blockIdx.x * 256 + threadIdx.x;
  if (i >= n4) return;
  float4 v = reinterpret_cast<float4*>(buf)[i];
  v.x = fmaxf(v.x, 0.f);
  v.y = fmaxf(v.y, 0.f);
  v.z = fmaxf(v.z, 0.f);
  v.w = fmaxf(v.w, 0.f);
  reinterpret_cast<float4*>(buf)[i] = v;
}

extern "C" void kernel_launch(void* const* d_in, const int* in_sizes, int n_in,
                              void* d_out, int out_size, void* d_ws, size_t ws_size,
                              hipStream_t stream) {
  const float* x0     = (const float*)d_in[0];
  const float* basis  = (const float*)d_in[1];
  const float* coeff  = (const float*)d_in[2];
  const float* self_w = (const float*)d_in[3];
  const float* bias   = (const float*)d_in[4];
  const int*   eidx   = (const int*)d_in[5];
  const int*   etyp   = (const int*)d_in[6];

  const int N  = in_sizes[0] / DD;
  const int L  = in_sizes[4] / DD;
  const int Bn = in_sizes[1] / (L * DD * DD);
  const int R  = in_sizes[2] / (L * Bn);
  const int E  = in_sizes[6];

  const int* esrc = eidx;
  const int* edst = eidx + E;

  // ---- workspace layout: u32 region first, then floats ----
  u32* cnt      = (u32*)d_ws;          // N   (also zeroed together with fill)
  u32* fill     = cnt + N;             // N
  u32* row_ptr  = fill + N;            // N+1
  u32* partials = row_ptr + N + 1;     // up to 1024
  u32* packed   = partials + 1024;     // E
  size_t int_u32 = (size_t)3 * N + 1 + 1024 + E;
  size_t falign  = (int_u32 * 4 + 15) / 16 * 16;   // byte offset, 16B aligned
  float* Wbuf = (float*)((char*)d_ws + falign);    // R*DD*DD
  float* A    = Wbuf + (size_t)R * DD * DD;        // N*DD
  float* h    = A + (size_t)N * DD;                // chunk*N*DD

  size_t avail = ws_size / sizeof(float);
  size_t fixed = falign / 4 + (size_t)R * DD * DD + (size_t)N * DD;
  int chunk = 1;
  if (avail > fixed + (size_t)N * DD) {
    size_t c = (avail - fixed) / ((size_t)N * DD);
    chunk = (int)(c > (size_t)R ? (size_t)R : c);
  }

  const int NB_SCAN = (N + 1023) / 1024;
  const int NB3     = (N + 1 + 1023) / 1024;
  const int nb_x    = (N + DD - 1) / DD;
  const int nb_e    = (E + 255) / 256;
  const int n4      = (N * DD) / 4;
  const int nb_agg  = (N * 64 + 255) / 256;

  // ---- build CSR (once; edges constant across layers) ----
  zero_u32_kernel<<<(2 * N + 255) / 256, 256, 0, stream>>>(cnt, 2 * N);
  hist_kernel<<<nb_e, 256, 0, stream>>>(edst, cnt, E);
  scan1_kernel<<<NB_SCAN, 1024, 0, stream>>>(cnt, row_ptr, partials, N);
  scan2_kernel<<<1, 64, 0, stream>>>(partials, NB_SCAN);
  scan3_kernel<<<NB3, 1024, 0, stream>>>(row_ptr, partials, N, E);
  scatter_kernel<<<nb_e, 256, 0, stream>>>(esrc, edst, etyp, row_ptr, fill, packed, E);

  // ---- layers ----
  for (int l = 0; l < L; ++l) {
    const float* xin = (l == 0) ? x0 : A;
    float* outf      = (l == L - 1) ? (float*)d_out : A;

    compute_w_kernel<<<(R * DD * DD + 255) / 256, 256, 0, stream>>>(
        basis + (size_t)l * Bn * DD * DD, coeff + (size_t)l * R * Bn, Wbuf, R, Bn);

    for (int c0 = 0; c0 < R; c0 += chunk) {
      int cs = (R - c0 < chunk) ? (R - c0) : chunk;
      int gy = cs + ((c0 == 0) ? 1 : 0);   // self-loop block rides on first chunk
      transform_kernel<<<dim3(nb_x, gy), 256, 0, stream>>>(
          xin, Wbuf + (size_t)c0 * DD * DD, self_w + (size_t)l * DD * DD,
          bias + (size_t)l * DD, h, outf, N, cs);
      aggregate_kernel<<<nb_agg, 256, 0, stream>>>(
          packed, row_ptr, h, outf, N, c0, c0 + cs);
    }

    relu_kernel<<<(n4 + 255) / 256, 256, 0, stream>>>(outf, n4);
  }
}